// Round 5
// baseline (267.529 us; speedup 1.0000x reference)
//
#include <hip/hip_runtime.h>

#define N_NODES 4096
#define N_EDGES 131072
#define DIM     256
#define HEADS   8
#define HDIM    32
#define MAXDEG  320
#define MAXDEGP 321

typedef unsigned short u16;
typedef unsigned int   u32;

using f32x4  = __attribute__((ext_vector_type(4))) float;
using bf16x8 = __attribute__((ext_vector_type(8))) short;
using u16x8  = __attribute__((ext_vector_type(8))) unsigned short;

__device__ __forceinline__ u16 f2bf(float f) {
  u32 u = __float_as_uint(f);
  u += 0x7fffu + ((u >> 16) & 1u);   // RNE
  return (u16)(u >> 16);
}

__device__ __forceinline__ float dot4(float4 a, float4 b) {
  return a.x * b.x + a.y * b.y + a.z * b.z + a.w * b.w;
}

// ---------------------------------------------------------------------------
// Weight prep
// ---------------------------------------------------------------------------
__global__ __launch_bounds__(256) void prep_w_k(
    const float* __restrict__ Wq, const float* __restrict__ Wk,
    const float* __restrict__ Wv, const float* __restrict__ Wi,
    const float* __restrict__ We, const float* __restrict__ Wo,
    const float* __restrict__ bq, const float* __restrict__ bk,
    const float* __restrict__ bv, const float* __restrict__ bi,
    u16* __restrict__ WcatT, u16* __restrict__ WeT, u16* __restrict__ WoT,
    float* __restrict__ bcat)
{
  int n = blockIdx.x;
  int k = threadIdx.x;
  if (n < 1024) {
    const float* W = (n < 256) ? Wq : (n < 512) ? Wk : (n < 768) ? Wv : Wi;
    int nn = n & 255;
    WcatT[(size_t)n * 256 + k] = f2bf(W[(size_t)k * 256 + nn]);
    if (k == 0) {
      const float* b = (n < 256) ? bq : (n < 512) ? bk : (n < 768) ? bv : bi;
      bcat[n] = b[nn];
    }
  } else if (n < 1280) {
    int nn = n - 1024;
    WeT[(size_t)nn * 256 + k] = f2bf(We[(size_t)k * 256 + nn]);
  } else {
    int nn = n - 1280;
    WoT[(size_t)nn * 256 + k] = f2bf(Wo[(size_t)k * 256 + nn]);
  }
}

// ---------------------------------------------------------------------------
// Direct-register GEMM: C[M x Nn] = A(fp32, M x 256) @ B + bias.
// BT (Nn x 256) = B^T bf16. NO LDS, NO barriers: MFMA fragments are loaded
// straight from global (A: 32B/lane fp32 -> bf16 in reg; B: 16B/lane).
// Wave reads are naturally coalesced (16 rows x 128B per kt). wc/wr operand
// duplication is absorbed by L1/L2. Each wave streams independently; the
// compiler pipelines loads across kt (addresses fold to base + imm offset).
// Lane holds C[m = mi*16+fr][n = ni*16+hi*4+reg] (mfma(b,a,acc) swap).
// ---------------------------------------------------------------------------
__global__ __launch_bounds__(256) void gemm4_k(
    const float* __restrict__ Afp, const u16* __restrict__ BT,
    const float* __restrict__ bias, float* __restrict__ C, int Nn)
{
  const int n0 = blockIdx.x * 128;
  const int m0 = blockIdx.y * 128;
  const int tid = threadIdx.x;
  const int w = tid >> 6, l = tid & 63;
  const int wr = w >> 1, wc = w & 1;
  const int fr = l & 15, hi = l >> 4;

  const float* A0 = Afp + (size_t)(m0 + wr * 64 + fr) * 256 + hi * 8;
  const u16*   B0 = BT  + (size_t)(n0 + wc * 64 + fr) * 256 + hi * 8;

  f32x4 acc[4][4] = {};

#pragma unroll 2
  for (int kt = 0; kt < 8; ++kt) {
    bf16x8 a[4], b[4];
#pragma unroll
    for (int mi = 0; mi < 4; ++mi) {
      const float* p = A0 + (size_t)mi * 16 * 256 + kt * 32;
      float4 lo = *(const float4*)p;
      float4 hi4 = *(const float4*)(p + 4);
      u16x8 u;
      u[0] = f2bf(lo.x);  u[1] = f2bf(lo.y);  u[2] = f2bf(lo.z);  u[3] = f2bf(lo.w);
      u[4] = f2bf(hi4.x); u[5] = f2bf(hi4.y); u[6] = f2bf(hi4.z); u[7] = f2bf(hi4.w);
      a[mi] = *(bf16x8*)&u;
    }
#pragma unroll
    for (int ni = 0; ni < 4; ++ni)
      b[ni] = *(const bf16x8*)(B0 + (size_t)ni * 16 * 256 + kt * 32);
#pragma unroll
    for (int mi = 0; mi < 4; ++mi)
#pragma unroll
      for (int ni = 0; ni < 4; ++ni)
        acc[mi][ni] = __builtin_amdgcn_mfma_f32_16x16x32_bf16(
            b[ni], a[mi], acc[mi][ni], 0, 0, 0);
  }

  // C write: float4 per (mi,ni)
#pragma unroll
  for (int mi = 0; mi < 4; ++mi) {
    int row = m0 + wr * 64 + mi * 16 + fr;
#pragma unroll
    for (int ni = 0; ni < 4; ++ni) {
      int col = n0 + wc * 64 + ni * 16 + hi * 4;
      float4 bv = *(const float4*)&bias[col];
      f32x4 v = acc[mi][ni];
      float4 o;
      o.x = v[0] + bv.x; o.y = v[1] + bv.y; o.z = v[2] + bv.z; o.w = v[3] + bv.w;
      *(float4*)&C[(size_t)row * Nn + col] = o;
    }
  }
}

// ---------------------------------------------------------------------------
// CSR build
// ---------------------------------------------------------------------------
__global__ __launch_bounds__(256) void hist_k(const int* __restrict__ src, int* __restrict__ deg)
{
  int e = blockIdx.x * 256 + threadIdx.x;
  if (e < N_EDGES) atomicAdd(&deg[src[e]], 1);
}

__global__ __launch_bounds__(1024) void scan_k(const int* __restrict__ deg,
                                               int* __restrict__ rowstart,
                                               int* __restrict__ cursor)
{
  __shared__ int s[1024];
  int tid = threadIdx.x;
  int4 v = ((const int4*)deg)[tid];
  int sum = v.x + v.y + v.z + v.w;
  s[tid] = sum;
  __syncthreads();
  for (int off = 1; off < 1024; off <<= 1) {
    int t = (tid >= off) ? s[tid - off] : 0;
    __syncthreads();
    s[tid] += t;
    __syncthreads();
  }
  int excl = s[tid] - sum;
  int r0 = excl, r1 = excl + v.x, r2 = r1 + v.y, r3 = r2 + v.z;
  rowstart[4 * tid + 0] = r0; cursor[4 * tid + 0] = r0;
  rowstart[4 * tid + 1] = r1; cursor[4 * tid + 1] = r1;
  rowstart[4 * tid + 2] = r2; cursor[4 * tid + 2] = r2;
  rowstart[4 * tid + 3] = r3; cursor[4 * tid + 3] = r3;
  if (tid == 1023) rowstart[4096] = r3 + v.w;
}

__global__ __launch_bounds__(256) void scatter_k(const int* __restrict__ src,
                                                 int* __restrict__ cursor,
                                                 int* __restrict__ csr)
{
  int e = blockIdx.x * 256 + threadIdx.x;
  if (e < N_EDGES) {
    int p = atomicAdd(&cursor[src[e]], 1);
    csr[p] = e;
  }
}

// ---------------------------------------------------------------------------
// Fused per-node kernel: edge logits + sparse softmax + V aggregation.
// ---------------------------------------------------------------------------
__global__ __launch_bounds__(256) void node_attn_k(
    const float* __restrict__ QKVI, const float* __restrict__ Ef,
    const int* __restrict__ rowstart, const int* __restrict__ csr,
    const int* __restrict__ tgt, float* __restrict__ agg)
{
  __shared__ int   s_eid[MAXDEG];
  __shared__ int   s_tgt[MAXDEG];
  __shared__ float s_sc[HEADS][MAXDEGP];   // scores, then weights in-place
  __shared__ unsigned char s_alive[MAXDEG];
  __shared__ float s_self[8];
  __shared__ float s_wself[8];

  const float scl = 0.17677669529663687f;
  int i = blockIdx.x;
  int base = rowstart[i];
  int deg = rowstart[i + 1] - base;
  if (deg > MAXDEG) deg = MAXDEG;
  int tid = threadIdx.x;
  int w = tid >> 6, l = tid & 63;
  int h = tid >> 5, d = tid & 31;

  for (int t = tid; t < deg; t += 256) {
    int e = csr[base + t];
    s_eid[t] = e;
    s_tgt[t] = tgt[e];
  }
  __syncthreads();

  // Q_i: lane l holds dims 4l..4l+3 (head = l>>3)
  float4 q4 = *(const float4*)&QKVI[(size_t)i * 1024 + 4 * l];

  // self score (wave 0): Q_i . K_i per head
  if (w == 0) {
    float4 k4 = *(const float4*)&QKVI[(size_t)i * 1024 + 256 + 4 * l];
    float c = dot4(q4, k4);
#pragma unroll
    for (int off = 1; off <= 4; off <<= 1) c += __shfl_xor(c, off);
    if ((l & 7) == 0) s_self[l >> 3] = c * scl;
  }

  // edge logits: waves split edges; logit = ef.(q+k) + q.k per head
  for (int t = w; t < deg; t += 4) {
    int e = s_eid[t], tt = s_tgt[t];
    float4 ef = *(const float4*)&Ef[(size_t)e * 256 + 4 * l];
    float4 k4 = *(const float4*)&QKVI[(size_t)tt * 1024 + 256 + 4 * l];
    float c = dot4(q4, ef) + dot4(ef, k4) + dot4(q4, k4);
#pragma unroll
    for (int off = 1; off <= 4; off <<= 1) c += __shfl_xor(c, off);
    if ((l & 7) == 0) s_sc[l >> 3][t] = c * scl;
  }

  // dedup (keep max eid per tgt), drop self-target
  for (int t = tid; t < deg; t += 256) {
    int tt = s_tgt[t], ee = s_eid[t];
    bool alive = (tt != i);
    if (alive)
      for (int u = 0; u < deg; ++u)
        if (s_tgt[u] == tt && s_eid[u] > ee) { alive = false; break; }
    s_alive[t] = alive ? 1 : 0;
  }
  __syncthreads();

  // softmax: 32 lanes per head, in-place weights
  {
    float m = s_self[h];
    for (int t = d; t < deg; t += 32)
      if (s_alive[t]) m = fmaxf(m, s_sc[h][t]);
#pragma unroll
    for (int off = 16; off > 0; off >>= 1) m = fmaxf(m, __shfl_xor(m, off, 32));
    float lsum = 0.f;
    for (int t = d; t < deg; t += 32) {
      float wv = s_alive[t] ? expf(s_sc[h][t] - m) : 0.f;
      s_sc[h][t] = wv;
      lsum += wv;
    }
#pragma unroll
    for (int off = 16; off > 0; off >>= 1) lsum += __shfl_xor(lsum, off, 32);
    float wself = expf(s_self[h] - m);
    float inv = 1.f / (lsum + wself);
    if (d == 0) s_wself[h] = wself * inv;
    for (int t = d; t < deg; t += 32) s_sc[h][t] *= inv;
  }
  __syncthreads();

  // aggregate V (cols 512..767 of QKVI); col = tid -> coalesced
  int col = tid;
  float accv = s_wself[h] * QKVI[(size_t)i * 1024 + 512 + col];
  for (int t = 0; t < deg; ++t)
    if (s_alive[t])
      accv += s_sc[h][t] * QKVI[(size_t)s_tgt[t] * 1024 + 512 + col];
  agg[(size_t)i * 256 + col] = accv;
}

// ---------------------------------------------------------------------------
// LayerNorm(x_proj + preo)
// ---------------------------------------------------------------------------
__global__ __launch_bounds__(256) void ln_k(
    const float* __restrict__ QKVI, const float* __restrict__ preo,
    const float* __restrict__ g, const float* __restrict__ b,
    float* __restrict__ out)
{
  int i = blockIdx.x, c = threadIdx.x;
  float v = QKVI[(size_t)i * 1024 + 768 + c] + preo[(size_t)i * 256 + c];
  float s1 = v, s2 = v * v;
#pragma unroll
  for (int off = 32; off > 0; off >>= 1) {
    s1 += __shfl_xor(s1, off, 64);
    s2 += __shfl_xor(s2, off, 64);
  }
  __shared__ float r1[4], r2[4];
  int w = c >> 6;
  if ((c & 63) == 0) { r1[w] = s1; r2[w] = s2; }
  __syncthreads();
  s1 = r1[0] + r1[1] + r1[2] + r1[3];
  s2 = r2[0] + r2[1] + r2[2] + r2[3];
  float mu  = s1 * (1.0f / 256.0f);
  float var = s2 * (1.0f / 256.0f) - mu * mu;
  out[(size_t)i * 256 + c] = (v - mu) * rsqrtf(var + 1e-5f) * g[c] + b[c];
}

// ---------------------------------------------------------------------------
extern "C" void kernel_launch(void* const* d_in, const int* in_sizes, int n_in,
                              void* d_out, int out_size, void* d_ws, size_t ws_size,
                              hipStream_t stream) {
  (void)in_sizes; (void)n_in; (void)out_size; (void)ws_size;
  const float* x  = (const float*)d_in[0];
  const int*   ei = (const int*)d_in[1];
  const float* ea = (const float*)d_in[2];
  const float* Wq = (const float*)d_in[3];  const float* bq = (const float*)d_in[4];
  const float* Wk = (const float*)d_in[5];  const float* bk = (const float*)d_in[6];
  const float* Wv = (const float*)d_in[7];  const float* bv = (const float*)d_in[8];
  const float* We = (const float*)d_in[9];  const float* be = (const float*)d_in[10];
  const float* Wo = (const float*)d_in[11]; const float* bo = (const float*)d_in[12];
  const float* Wi = (const float*)d_in[13]; const float* bi = (const float*)d_in[14];
  const float* lng = (const float*)d_in[15]; const float* lnb = (const float*)d_in[16];

  const int* src = ei;
  const int* tgt = ei + N_EDGES;

  char* ws = (char*)d_ws;
  u16*   WcatT   = (u16*)(ws + 0);              //  512 KB
  u16*   WeT     = (u16*)(ws + 524288);         //  128 KB
  u16*   WoT     = (u16*)(ws + 655360);         //  128 KB
  float* bcat    = (float*)(ws + 786432);       //    4 KB
  float* QKVI    = (float*)(ws + 790528);       //   16 MB
  int*   deg     = (int*)(ws + 17567744);       //   16 KB
  int*   rowstart= (int*)(ws + 17584128);       //   16.25 KB
  int*   cursor  = (int*)(ws + 17600768);       //   16 KB
  int*   csr     = (int*)(ws + 17617152);       //  512 KB
  float* agg     = (float*)(ws + 18141440);     //    4 MB
  float* preo    = (float*)(ws + 22335744);     //    4 MB

  float* outN = (float*)d_out;
  float* outE = (float*)d_out + (size_t)N_NODES * DIM;

  hipMemsetAsync(deg, 0, N_NODES * sizeof(int), stream);

  prep_w_k<<<1536, 256, 0, stream>>>(Wq, Wk, Wv, Wi, We, Wo, bq, bk, bv, bi,
                                     WcatT, WeT, WoT, bcat);

  hist_k<<<N_EDGES / 256, 256, 0, stream>>>(src, deg);
  scan_k<<<1, 1024, 0, stream>>>(deg, rowstart, cursor);
  scatter_k<<<N_EDGES / 256, 256, 0, stream>>>(src, cursor, csr);

  // QKVI = x @ [Wq|Wk|Wv|Wi] + bcat
  gemm4_k<<<dim3(8, 32), 256, 0, stream>>>(x, WcatT, bcat, QKVI, 1024);

  // edge_out = edge_attr @ We + be
  gemm4_k<<<dim3(2, 1024), 256, 0, stream>>>(ea, WeT, be, outE, 256);

  // fused logits + softmax + V aggregation
  node_attn_k<<<N_NODES, 256, 0, stream>>>(QKVI, outE, rowstart, csr, tgt, agg);

  // preo = agg @ Wo + bo
  gemm4_k<<<dim3(2, 32), 256, 0, stream>>>(agg, WoT, bo, preo, 256);

  ln_k<<<N_NODES, 256, 0, stream>>>(QKVI, preo, lng, lnb, outN);
}

// Round 6
// 216.348 us; speedup vs baseline: 1.2366x; 1.2366x over previous
//
#include <hip/hip_runtime.h>

#define N_NODES 4096
#define N_EDGES 131072
#define DIM     256
#define HEADS   8
#define HDIM    32
#define MAXDEG  320
#define MAXDEGP 321

typedef unsigned short u16;
typedef unsigned int   u32;

using f32x4  = __attribute__((ext_vector_type(4))) float;
using bf16x8 = __attribute__((ext_vector_type(8))) short;
using u16x4  = __attribute__((ext_vector_type(4))) unsigned short;
using u16x8  = __attribute__((ext_vector_type(8))) unsigned short;

__device__ __forceinline__ u16 f2bf(float f) {
  u32 u = __float_as_uint(f);
  u += 0x7fffu + ((u >> 16) & 1u);   // RNE
  return (u16)(u >> 16);
}

__device__ __forceinline__ float dot4(float4 a, float4 b) {
  return a.x * b.x + a.y * b.y + a.z * b.z + a.w * b.w;
}

// ---------------------------------------------------------------------------
// Weight prep
// ---------------------------------------------------------------------------
__global__ __launch_bounds__(256) void prep_w_k(
    const float* __restrict__ Wq, const float* __restrict__ Wk,
    const float* __restrict__ Wv, const float* __restrict__ Wi,
    const float* __restrict__ We, const float* __restrict__ Wo,
    const float* __restrict__ bq, const float* __restrict__ bk,
    const float* __restrict__ bv, const float* __restrict__ bi,
    u16* __restrict__ WcatT, u16* __restrict__ WeT, u16* __restrict__ WoT,
    float* __restrict__ bcat)
{
  int n = blockIdx.x;
  int k = threadIdx.x;
  if (n < 1024) {
    const float* W = (n < 256) ? Wq : (n < 512) ? Wk : (n < 768) ? Wv : Wi;
    int nn = n & 255;
    WcatT[(size_t)n * 256 + k] = f2bf(W[(size_t)k * 256 + nn]);
    if (k == 0) {
      const float* b = (n < 256) ? bq : (n < 512) ? bk : (n < 768) ? bv : bi;
      bcat[n] = b[nn];
    }
  } else if (n < 1280) {
    int nn = n - 1024;
    WeT[(size_t)nn * 256 + k] = f2bf(We[(size_t)k * 256 + nn]);
  } else {
    int nn = n - 1280;
    WoT[(size_t)nn * 256 + k] = f2bf(Wo[(size_t)k * 256 + nn]);
  }
}

// ---------------------------------------------------------------------------
// 128x128 GEMM (for Nn=1024): C = A(fp32) @ B + bias, BT = B^T bf16.
// LDS dbuf, reg prefetch, lgkmcnt-only barrier, XOR swizzle. Lane holds
// C[m=mi*16+fr][n=ni*16+hi*4+reg] via mfma(b,a,acc) swap -> float4 stores.
// ---------------------------------------------------------------------------
__global__ __launch_bounds__(256) void gemm128_k(
    const float* __restrict__ Afp, const u16* __restrict__ BT,
    const float* __restrict__ bias, float* __restrict__ C, int Nn)
{
  __shared__ u16 As[2][128 * 32];
  __shared__ u16 Bs[2][128 * 32];
  const int n0 = blockIdx.x * 128;
  const int m0 = blockIdx.y * 128;
  const int tid = threadIdx.x;
  const int w = tid >> 6, l = tid & 63;
  const int wr = w >> 1, wc = w & 1;
  const int fr = l & 15, hi = l >> 4;

  float4 pa[4];
  u16x8  pb[2];
  f32x4  acc[4][4] = {};

  auto loadstep = [&](int kt) {
#pragma unroll
    for (int i = 0; i < 4; ++i) {
      int j = tid + 256 * i;
      pa[i] = *(const float4*)(Afp + (size_t)(m0 + (j >> 3)) * 256 + kt * 32 + ((j & 7) << 2));
    }
#pragma unroll
    for (int i = 0; i < 2; ++i) {
      int j = tid + 256 * i;
      pb[i] = *(const u16x8*)(BT + (size_t)(n0 + (j >> 2)) * 256 + kt * 32 + ((j & 3) << 3));
    }
  };
  auto storestep = [&](int buf) {
#pragma unroll
    for (int i = 0; i < 4; ++i) {
      int j = tid + 256 * i;
      int row = j >> 3;
      int c16 = (j & 7) >> 1, half = j & 1;
      int swc = (c16 + ((row >> 1) & 3)) & 3;
      u16x4 u;
      u.x = f2bf(pa[i].x); u.y = f2bf(pa[i].y); u.z = f2bf(pa[i].z); u.w = f2bf(pa[i].w);
      *(u16x4*)&As[buf][row * 32 + swc * 8 + half * 4] = u;
    }
#pragma unroll
    for (int i = 0; i < 2; ++i) {
      int j = tid + 256 * i;
      int row = j >> 2;
      int swc = ((j & 3) + ((row >> 1) & 3)) & 3;
      *(u16x8*)&Bs[buf][row * 32 + swc * 8] = pb[i];
    }
  };

  loadstep(0);
  storestep(0);

#pragma unroll
  for (int kt = 0; kt < 8; ++kt) {
    if (kt < 7) loadstep(kt + 1);
    __builtin_amdgcn_sched_barrier(0);
    asm volatile("s_waitcnt lgkmcnt(0)" ::: "memory");
    __builtin_amdgcn_s_barrier();
    __builtin_amdgcn_sched_barrier(0);
    const int cur = kt & 1;
    bf16x8 a[4], b[4];
#pragma unroll
    for (int mi = 0; mi < 4; ++mi) {
      int rA = wr * 64 + mi * 16 + fr;
      int swc = (hi + ((rA >> 1) & 3)) & 3;
      a[mi] = *(const bf16x8*)&As[cur][rA * 32 + swc * 8];
    }
#pragma unroll
    for (int ni = 0; ni < 4; ++ni) {
      int rB = wc * 64 + ni * 16 + fr;
      int swc = (hi + ((rB >> 1) & 3)) & 3;
      b[ni] = *(const bf16x8*)&Bs[cur][rB * 32 + swc * 8];
    }
#pragma unroll
    for (int mi = 0; mi < 4; ++mi)
#pragma unroll
      for (int ni = 0; ni < 4; ++ni)
        acc[mi][ni] = __builtin_amdgcn_mfma_f32_16x16x32_bf16(
            b[ni], a[mi], acc[mi][ni], 0, 0, 0);
    if (kt < 7) storestep((kt + 1) & 1);
  }

#pragma unroll
  for (int mi = 0; mi < 4; ++mi) {
    int row = m0 + wr * 64 + mi * 16 + fr;
#pragma unroll
    for (int ni = 0; ni < 4; ++ni) {
      int col = n0 + wc * 64 + ni * 16 + hi * 4;
      float4 bv = *(const float4*)&bias[col];
      f32x4 v = acc[mi][ni];
      float4 o;
      o.x = v[0] + bv.x; o.y = v[1] + bv.y; o.z = v[2] + bv.z; o.w = v[3] + bv.w;
      *(float4*)&C[(size_t)row * Nn + col] = o;
    }
  }
}

// ---------------------------------------------------------------------------
// 64x256 GEMM (for Nn=256): grid-x = 1 -> each A row fetched from HBM exactly
// once (no cross-XCD duplicate). B panel 128KB bf16 -> L2-resident. 4 waves,
// wave w owns cols [64w,64w+64). Same dbuf/swizzle/barrier discipline.
// ---------------------------------------------------------------------------
__global__ __launch_bounds__(256) void gemm64_k(
    const float* __restrict__ Afp, const u16* __restrict__ BT,
    const float* __restrict__ bias, float* __restrict__ C)
{
  __shared__ u16 As[2][64 * 32];
  __shared__ u16 Bs[2][256 * 32];
  const int m0 = blockIdx.x * 64;
  const int tid = threadIdx.x;
  const int w = tid >> 6, l = tid & 63;
  const int fr = l & 15, hi = l >> 4;

  float4 pa[2];
  u16x8  pb[4];
  f32x4  acc[4][4] = {};

  auto loadstep = [&](int kt) {
#pragma unroll
    for (int i = 0; i < 2; ++i) {
      int j = tid + 256 * i;            // 512 float4 chunks: row=j>>3, col=(j&7)*4
      pa[i] = *(const float4*)(Afp + (size_t)(m0 + (j >> 3)) * 256 + kt * 32 + ((j & 7) << 2));
    }
#pragma unroll
    for (int i = 0; i < 4; ++i) {
      int j = tid + 256 * i;            // 1024 u16x8 chunks: row=j>>2, col=(j&3)*8
      pb[i] = *(const u16x8*)(BT + (size_t)(j >> 2) * 256 + kt * 32 + ((j & 3) << 3));
    }
  };
  auto storestep = [&](int buf) {
#pragma unroll
    for (int i = 0; i < 2; ++i) {
      int j = tid + 256 * i;
      int row = j >> 3;
      int c16 = (j & 7) >> 1, half = j & 1;
      int swc = (c16 + ((row >> 1) & 3)) & 3;
      u16x4 u;
      u.x = f2bf(pa[i].x); u.y = f2bf(pa[i].y); u.z = f2bf(pa[i].z); u.w = f2bf(pa[i].w);
      *(u16x4*)&As[buf][row * 32 + swc * 8 + half * 4] = u;
    }
#pragma unroll
    for (int i = 0; i < 4; ++i) {
      int j = tid + 256 * i;
      int row = j >> 2;
      int swc = ((j & 3) + ((row >> 1) & 3)) & 3;
      *(u16x8*)&Bs[buf][row * 32 + swc * 8] = pb[i];
    }
  };

  loadstep(0);
  storestep(0);

#pragma unroll
  for (int kt = 0; kt < 8; ++kt) {
    if (kt < 7) loadstep(kt + 1);
    __builtin_amdgcn_sched_barrier(0);
    asm volatile("s_waitcnt lgkmcnt(0)" ::: "memory");
    __builtin_amdgcn_s_barrier();
    __builtin_amdgcn_sched_barrier(0);
    const int cur = kt & 1;
    bf16x8 a[4], b[4];
#pragma unroll
    for (int mi = 0; mi < 4; ++mi) {
      int rA = mi * 16 + fr;
      int swc = (hi + ((rA >> 1) & 3)) & 3;
      a[mi] = *(const bf16x8*)&As[cur][rA * 32 + swc * 8];
    }
#pragma unroll
    for (int ni = 0; ni < 4; ++ni) {
      int rB = w * 64 + ni * 16 + fr;
      int swc = (hi + ((rB >> 1) & 3)) & 3;
      b[ni] = *(const bf16x8*)&Bs[cur][rB * 32 + swc * 8];
    }
#pragma unroll
    for (int mi = 0; mi < 4; ++mi)
#pragma unroll
      for (int ni = 0; ni < 4; ++ni)
        acc[mi][ni] = __builtin_amdgcn_mfma_f32_16x16x32_bf16(
            b[ni], a[mi], acc[mi][ni], 0, 0, 0);
    if (kt < 7) storestep((kt + 1) & 1);
  }

#pragma unroll
  for (int mi = 0; mi < 4; ++mi) {
    int row = m0 + mi * 16 + fr;
#pragma unroll
    for (int ni = 0; ni < 4; ++ni) {
      int col = w * 64 + ni * 16 + hi * 4;
      float4 bv = *(const float4*)&bias[col];
      f32x4 v = acc[mi][ni];
      float4 o;
      o.x = v[0] + bv.x; o.y = v[1] + bv.y; o.z = v[2] + bv.z; o.w = v[3] + bv.w;
      *(float4*)&C[(size_t)row * 256 + col] = o;
    }
  }
}

// ---------------------------------------------------------------------------
// CSR build
// ---------------------------------------------------------------------------
__global__ __launch_bounds__(256) void hist_k(const int* __restrict__ src, int* __restrict__ deg)
{
  int e = blockIdx.x * 256 + threadIdx.x;
  if (e < N_EDGES) atomicAdd(&deg[src[e]], 1);
}

__global__ __launch_bounds__(1024) void scan_k(const int* __restrict__ deg,
                                               int* __restrict__ rowstart,
                                               int* __restrict__ cursor)
{
  __shared__ int s[1024];
  int tid = threadIdx.x;
  int4 v = ((const int4*)deg)[tid];
  int sum = v.x + v.y + v.z + v.w;
  s[tid] = sum;
  __syncthreads();
  for (int off = 1; off < 1024; off <<= 1) {
    int t = (tid >= off) ? s[tid - off] : 0;
    __syncthreads();
    s[tid] += t;
    __syncthreads();
  }
  int excl = s[tid] - sum;
  int r0 = excl, r1 = excl + v.x, r2 = r1 + v.y, r3 = r2 + v.z;
  rowstart[4 * tid + 0] = r0; cursor[4 * tid + 0] = r0;
  rowstart[4 * tid + 1] = r1; cursor[4 * tid + 1] = r1;
  rowstart[4 * tid + 2] = r2; cursor[4 * tid + 2] = r2;
  rowstart[4 * tid + 3] = r3; cursor[4 * tid + 3] = r3;
  if (tid == 1023) rowstart[4096] = r3 + v.w;
}

__global__ __launch_bounds__(256) void scatter_k(const int* __restrict__ src,
                                                 int* __restrict__ cursor,
                                                 int* __restrict__ csr)
{
  int e = blockIdx.x * 256 + threadIdx.x;
  if (e < N_EDGES) {
    int p = atomicAdd(&cursor[src[e]], 1);
    csr[p] = e;
  }
}

// ---------------------------------------------------------------------------
// Fused per-node kernel: edge logits + sparse softmax + V aggregation.
// ---------------------------------------------------------------------------
__global__ __launch_bounds__(256) void node_attn_k(
    const float* __restrict__ QKVI, const float* __restrict__ Ef,
    const int* __restrict__ rowstart, const int* __restrict__ csr,
    const int* __restrict__ tgt, float* __restrict__ agg)
{
  __shared__ int   s_eid[MAXDEG];
  __shared__ int   s_tgt[MAXDEG];
  __shared__ float s_sc[HEADS][MAXDEGP];   // scores, then weights in-place
  __shared__ unsigned char s_alive[MAXDEG];
  __shared__ float s_self[8];
  __shared__ float s_wself[8];

  const float scl = 0.17677669529663687f;
  int i = blockIdx.x;
  int base = rowstart[i];
  int deg = rowstart[i + 1] - base;
  if (deg > MAXDEG) deg = MAXDEG;
  int tid = threadIdx.x;
  int w = tid >> 6, l = tid & 63;
  int h = tid >> 5, d = tid & 31;

  for (int t = tid; t < deg; t += 256) {
    int e = csr[base + t];
    s_eid[t] = e;
    s_tgt[t] = tgt[e];
  }
  __syncthreads();

  // Q_i: lane l holds dims 4l..4l+3 (head = l>>3)
  float4 q4 = *(const float4*)&QKVI[(size_t)i * 1024 + 4 * l];

  // self score (wave 0): Q_i . K_i per head
  if (w == 0) {
    float4 k4 = *(const float4*)&QKVI[(size_t)i * 1024 + 256 + 4 * l];
    float c = dot4(q4, k4);
#pragma unroll
    for (int off = 1; off <= 4; off <<= 1) c += __shfl_xor(c, off);
    if ((l & 7) == 0) s_self[l >> 3] = c * scl;
  }

  // edge logits: waves split edges; logit = ef.(q+k) + q.k per head
  for (int t = w; t < deg; t += 4) {
    int e = s_eid[t], tt = s_tgt[t];
    float4 ef = *(const float4*)&Ef[(size_t)e * 256 + 4 * l];
    float4 k4 = *(const float4*)&QKVI[(size_t)tt * 1024 + 256 + 4 * l];
    float c = dot4(q4, ef) + dot4(ef, k4) + dot4(q4, k4);
#pragma unroll
    for (int off = 1; off <= 4; off <<= 1) c += __shfl_xor(c, off);
    if ((l & 7) == 0) s_sc[l >> 3][t] = c * scl;
  }

  // dedup (keep max eid per tgt), drop self-target
  for (int t = tid; t < deg; t += 256) {
    int tt = s_tgt[t], ee = s_eid[t];
    bool alive = (tt != i);
    if (alive)
      for (int u = 0; u < deg; ++u)
        if (s_tgt[u] == tt && s_eid[u] > ee) { alive = false; break; }
    s_alive[t] = alive ? 1 : 0;
  }
  __syncthreads();

  // softmax: 32 lanes per head, in-place weights
  {
    float m = s_self[h];
    for (int t = d; t < deg; t += 32)
      if (s_alive[t]) m = fmaxf(m, s_sc[h][t]);
#pragma unroll
    for (int off = 16; off > 0; off >>= 1) m = fmaxf(m, __shfl_xor(m, off, 32));
    float lsum = 0.f;
    for (int t = d; t < deg; t += 32) {
      float wv = s_alive[t] ? expf(s_sc[h][t] - m) : 0.f;
      s_sc[h][t] = wv;
      lsum += wv;
    }
#pragma unroll
    for (int off = 16; off > 0; off >>= 1) lsum += __shfl_xor(lsum, off, 32);
    float wself = expf(s_self[h] - m);
    float inv = 1.f / (lsum + wself);
    if (d == 0) s_wself[h] = wself * inv;
    for (int t = d; t < deg; t += 32) s_sc[h][t] *= inv;
  }
  __syncthreads();

  // aggregate V (cols 512..767 of QKVI); col = tid -> coalesced
  int col = tid;
  float accv = s_wself[h] * QKVI[(size_t)i * 1024 + 512 + col];
  for (int t = 0; t < deg; ++t)
    if (s_alive[t])
      accv += s_sc[h][t] * QKVI[(size_t)s_tgt[t] * 1024 + 512 + col];
  agg[(size_t)i * 256 + col] = accv;
}

// ---------------------------------------------------------------------------
// LayerNorm(x_proj + preo)
// ---------------------------------------------------------------------------
__global__ __launch_bounds__(256) void ln_k(
    const float* __restrict__ QKVI, const float* __restrict__ preo,
    const float* __restrict__ g, const float* __restrict__ b,
    float* __restrict__ out)
{
  int i = blockIdx.x, c = threadIdx.x;
  float v = QKVI[(size_t)i * 1024 + 768 + c] + preo[(size_t)i * 256 + c];
  float s1 = v, s2 = v * v;
#pragma unroll
  for (int off = 32; off > 0; off >>= 1) {
    s1 += __shfl_xor(s1, off, 64);
    s2 += __shfl_xor(s2, off, 64);
  }
  __shared__ float r1[4], r2[4];
  int w = c >> 6;
  if ((c & 63) == 0) { r1[w] = s1; r2[w] = s2; }
  __syncthreads();
  s1 = r1[0] + r1[1] + r1[2] + r1[3];
  s2 = r2[0] + r2[1] + r2[2] + r2[3];
  float mu  = s1 * (1.0f / 256.0f);
  float var = s2 * (1.0f / 256.0f) - mu * mu;
  out[(size_t)i * 256 + c] = (v - mu) * rsqrtf(var + 1e-5f) * g[c] + b[c];
}

// ---------------------------------------------------------------------------
extern "C" void kernel_launch(void* const* d_in, const int* in_sizes, int n_in,
                              void* d_out, int out_size, void* d_ws, size_t ws_size,
                              hipStream_t stream) {
  (void)in_sizes; (void)n_in; (void)out_size; (void)ws_size;
  const float* x  = (const float*)d_in[0];
  const int*   ei = (const int*)d_in[1];
  const float* ea = (const float*)d_in[2];
  const float* Wq = (const float*)d_in[3];  const float* bq = (const float*)d_in[4];
  const float* Wk = (const float*)d_in[5];  const float* bk = (const float*)d_in[6];
  const float* Wv = (const float*)d_in[7];  const float* bv = (const float*)d_in[8];
  const float* We = (const float*)d_in[9];  const float* be = (const float*)d_in[10];
  const float* Wo = (const float*)d_in[11]; const float* bo = (const float*)d_in[12];
  const float* Wi = (const float*)d_in[13]; const float* bi = (const float*)d_in[14];
  const float* lng = (const float*)d_in[15]; const float* lnb = (const float*)d_in[16];

  const int* src = ei;
  const int* tgt = ei + N_EDGES;

  char* ws = (char*)d_ws;
  u16*   WcatT   = (u16*)(ws + 0);              //  512 KB
  u16*   WeT     = (u16*)(ws + 524288);         //  128 KB
  u16*   WoT     = (u16*)(ws + 655360);         //  128 KB
  float* bcat    = (float*)(ws + 786432);       //    4 KB
  float* QKVI    = (float*)(ws + 790528);       //   16 MB
  int*   deg     = (int*)(ws + 17567744);       //   16 KB
  int*   rowstart= (int*)(ws + 17584128);       //   16.25 KB
  int*   cursor  = (int*)(ws + 17600768);       //   16 KB
  int*   csr     = (int*)(ws + 17617152);       //  512 KB
  float* agg     = (float*)(ws + 18141440);     //    4 MB
  float* preo    = (float*)(ws + 22335744);     //    4 MB

  float* outN = (float*)d_out;
  float* outE = (float*)d_out + (size_t)N_NODES * DIM;

  hipMemsetAsync(deg, 0, N_NODES * sizeof(int), stream);

  prep_w_k<<<1536, 256, 0, stream>>>(Wq, Wk, Wv, Wi, We, Wo, bq, bk, bv, bi,
                                     WcatT, WeT, WoT, bcat);

  hist_k<<<N_EDGES / 256, 256, 0, stream>>>(src, deg);
  scan_k<<<1, 1024, 0, stream>>>(deg, rowstart, cursor);
  scatter_k<<<N_EDGES / 256, 256, 0, stream>>>(src, cursor, csr);

  // QKVI = x @ [Wq|Wk|Wv|Wi] + bcat
  gemm128_k<<<dim3(8, 32), 256, 0, stream>>>(x, WcatT, bcat, QKVI, 1024);

  // edge_out = edge_attr @ We + be  (64x256 tile, A read once)
  gemm64_k<<<N_EDGES / 64, 256, 0, stream>>>(ea, WeT, be, outE);

  // fused logits + softmax + V aggregation
  node_attn_k<<<N_NODES, 256, 0, stream>>>(QKVI, outE, rowstart, csr, tgt, agg);

  // preo = agg @ Wo + bo
  gemm64_k<<<N_NODES / 64, 256, 0, stream>>>(agg, WoT, bo, preo);

  ln_k<<<N_NODES, 256, 0, stream>>>(QKVI, preo, lng, lnb, outN);
}

// Round 7
// 216.262 us; speedup vs baseline: 1.2371x; 1.0004x over previous
//
#include <hip/hip_runtime.h>

#define N_NODES 4096
#define N_EDGES 131072
#define DIM     256
#define HEADS   8
#define HDIM    32
#define MAXDEG  320
#define MAXDEGP 321

typedef unsigned short u16;
typedef unsigned int   u32;

using f32x4  = __attribute__((ext_vector_type(4))) float;
using bf16x8 = __attribute__((ext_vector_type(8))) short;
using u16x4  = __attribute__((ext_vector_type(4))) unsigned short;
using u16x8  = __attribute__((ext_vector_type(8))) unsigned short;

__device__ __forceinline__ u16 f2bf(float f) {
  u32 u = __float_as_uint(f);
  u += 0x7fffu + ((u >> 16) & 1u);   // RNE
  return (u16)(u >> 16);
}

__device__ __forceinline__ float dot4(float4 a, float4 b) {
  return a.x * b.x + a.y * b.y + a.z * b.z + a.w * b.w;
}

// ---------------------------------------------------------------------------
// Weight prep
// ---------------------------------------------------------------------------
__global__ __launch_bounds__(256) void prep_w_k(
    const float* __restrict__ Wq, const float* __restrict__ Wk,
    const float* __restrict__ Wv, const float* __restrict__ Wi,
    const float* __restrict__ We, const float* __restrict__ Wo,
    const float* __restrict__ bq, const float* __restrict__ bk,
    const float* __restrict__ bv, const float* __restrict__ bi,
    u16* __restrict__ WcatT, u16* __restrict__ WeT, u16* __restrict__ WoT,
    float* __restrict__ bcat)
{
  int n = blockIdx.x;
  int k = threadIdx.x;
  if (n < 1024) {
    const float* W = (n < 256) ? Wq : (n < 512) ? Wk : (n < 768) ? Wv : Wi;
    int nn = n & 255;
    WcatT[(size_t)n * 256 + k] = f2bf(W[(size_t)k * 256 + nn]);
    if (k == 0) {
      const float* b = (n < 256) ? bq : (n < 512) ? bk : (n < 768) ? bv : bi;
      bcat[n] = b[nn];
    }
  } else if (n < 1280) {
    int nn = n - 1024;
    WeT[(size_t)nn * 256 + k] = f2bf(We[(size_t)k * 256 + nn]);
  } else {
    int nn = n - 1280;
    WoT[(size_t)nn * 256 + k] = f2bf(Wo[(size_t)k * 256 + nn]);
  }
}

// ---------------------------------------------------------------------------
// 64-row GEMM body: C[m0..m0+64)[nc0..nc0+256) = A(fp32) @ B + bias.
// BT = B^T bf16 (stride 256). A staged through an 8KB LDS double-buffer
// (barrier = lgkmcnt-only); B fragments loaded DIRECTLY from global (L2-hot,
// compile-time offsets, issued before the barrier so they overlap it).
// 4 waves; wave w owns cols [nc0+64w, nc0+64w+64). Lane holds
// C[m=mi*16+fr][n=ni*16+hi*4+reg] via mfma(b,a,acc) swap -> float4 stores.
// ---------------------------------------------------------------------------
__device__ __forceinline__ void gemm64_body(
    const float* __restrict__ A, const u16* __restrict__ BT,
    const float* __restrict__ bias, float* __restrict__ C,
    int Nn, int m0, int nc0, u16 As[2][64 * 32])
{
  const int tid = threadIdx.x;
  const int w = tid >> 6, l = tid & 63;
  const int fr = l & 15, hi = l >> 4;

  float4 pa[2];
  f32x4  acc[4][4] = {};

  const u16* B0 = BT + (size_t)(nc0 + w * 64 + fr) * 256 + hi * 8;

  auto loadA = [&](int kt) {
#pragma unroll
    for (int i = 0; i < 2; ++i) {
      int j = tid + 256 * i;
      pa[i] = *(const float4*)(A + (size_t)(m0 + (j >> 3)) * 256 + kt * 32 + ((j & 7) << 2));
    }
  };
  auto storeA = [&](int buf) {
#pragma unroll
    for (int i = 0; i < 2; ++i) {
      int j = tid + 256 * i;
      int row = j >> 3;
      int c16 = (j & 7) >> 1, half = j & 1;
      int swc = (c16 + ((row >> 1) & 3)) & 3;
      u16x4 u;
      u.x = f2bf(pa[i].x); u.y = f2bf(pa[i].y); u.z = f2bf(pa[i].z); u.w = f2bf(pa[i].w);
      *(u16x4*)&As[buf][row * 32 + swc * 8 + half * 4] = u;
    }
  };

  loadA(0);
  storeA(0);

#pragma unroll
  for (int kt = 0; kt < 8; ++kt) {
    if (kt < 7) loadA(kt + 1);
    bf16x8 pb[4];
#pragma unroll
    for (int ni = 0; ni < 4; ++ni)
      pb[ni] = *(const bf16x8*)(B0 + (size_t)ni * 16 * 256 + kt * 32);
    __builtin_amdgcn_sched_barrier(0);
    asm volatile("s_waitcnt lgkmcnt(0)" ::: "memory");
    __builtin_amdgcn_s_barrier();
    __builtin_amdgcn_sched_barrier(0);
    const int cur = kt & 1;
    bf16x8 a[4];
#pragma unroll
    for (int mi = 0; mi < 4; ++mi) {
      int rA = mi * 16 + fr;
      int swc = (hi + ((rA >> 1) & 3)) & 3;
      a[mi] = *(const bf16x8*)&As[cur][rA * 32 + swc * 8];
    }
#pragma unroll
    for (int mi = 0; mi < 4; ++mi)
#pragma unroll
      for (int ni = 0; ni < 4; ++ni)
        acc[mi][ni] = __builtin_amdgcn_mfma_f32_16x16x32_bf16(
            pb[ni], a[mi], acc[mi][ni], 0, 0, 0);
    if (kt < 7) storeA((kt + 1) & 1);
  }

#pragma unroll
  for (int mi = 0; mi < 4; ++mi) {
    int row = m0 + mi * 16 + fr;
#pragma unroll
    for (int ni = 0; ni < 4; ++ni) {
      int col = nc0 + w * 64 + ni * 16 + hi * 4;
      float4 bv = *(const float4*)&bias[col];
      f32x4 v = acc[mi][ni];
      float4 o;
      o.x = v[0] + bv.x; o.y = v[1] + bv.y; o.z = v[2] + bv.z; o.w = v[3] + bv.w;
      *(float4*)&C[(size_t)row * Nn + col] = o;
    }
  }
}

// Merged dispatch: 2304 blocks = 2048 edge-GEMM + 256 QKVI-GEMM, interleaved
// (every 9th block is QKVI) so compute-dense QKVI blocks fill the edge
// blocks' memory-stall bubbles on every CU.
__global__ __launch_bounds__(256) void gemm_all_k(
    const float* __restrict__ ea, const u16* __restrict__ WeT,
    const float* __restrict__ be, float* __restrict__ outE,
    const float* __restrict__ x, const u16* __restrict__ WcatT,
    const float* __restrict__ bcat, float* __restrict__ QKVI)
{
  __shared__ u16 As[2][64 * 32];
  int bid = blockIdx.x;
  int r = bid % 9, q = bid / 9;
  if (r < 8) {
    int e = q * 8 + r;                       // 0..2047
    gemm64_body(ea, WeT, be, outE, 256, e * 64, 0, As);
  } else {
    int j = q;                               // 0..255
    gemm64_body(x, WcatT, bcat, QKVI, 1024, (j & 63) * 64, (j >> 6) * 256, As);
  }
}

// Standalone (Wo projection)
__global__ __launch_bounds__(256) void gemm64_k(
    const float* __restrict__ Afp, const u16* __restrict__ BT,
    const float* __restrict__ bias, float* __restrict__ C)
{
  __shared__ u16 As[2][64 * 32];
  gemm64_body(Afp, BT, bias, C, 256, blockIdx.x * 64, 0, As);
}

// ---------------------------------------------------------------------------
// CSR build
// ---------------------------------------------------------------------------
__global__ __launch_bounds__(256) void hist_k(const int* __restrict__ src, int* __restrict__ deg)
{
  int e = blockIdx.x * 256 + threadIdx.x;
  if (e < N_EDGES) atomicAdd(&deg[src[e]], 1);
}

__global__ __launch_bounds__(1024) void scan_k(const int* __restrict__ deg,
                                               int* __restrict__ rowstart,
                                               int* __restrict__ cursor)
{
  __shared__ int s[1024];
  int tid = threadIdx.x;
  int4 v = ((const int4*)deg)[tid];
  int sum = v.x + v.y + v.z + v.w;
  s[tid] = sum;
  __syncthreads();
  for (int off = 1; off < 1024; off <<= 1) {
    int t = (tid >= off) ? s[tid - off] : 0;
    __syncthreads();
    s[tid] += t;
    __syncthreads();
  }
  int excl = s[tid] - sum;
  int r0 = excl, r1 = excl + v.x, r2 = r1 + v.y, r3 = r2 + v.z;
  rowstart[4 * tid + 0] = r0; cursor[4 * tid + 0] = r0;
  rowstart[4 * tid + 1] = r1; cursor[4 * tid + 1] = r1;
  rowstart[4 * tid + 2] = r2; cursor[4 * tid + 2] = r2;
  rowstart[4 * tid + 3] = r3; cursor[4 * tid + 3] = r3;
  if (tid == 1023) rowstart[4096] = r3 + v.w;
}

__global__ __launch_bounds__(256) void scatter_k(const int* __restrict__ src,
                                                 int* __restrict__ cursor,
                                                 int* __restrict__ csr)
{
  int e = blockIdx.x * 256 + threadIdx.x;
  if (e < N_EDGES) {
    int p = atomicAdd(&cursor[src[e]], 1);
    csr[p] = e;
  }
}

// ---------------------------------------------------------------------------
// Fused per-node kernel: edge logits + sparse softmax + V aggregation.
// ---------------------------------------------------------------------------
__global__ __launch_bounds__(256) void node_attn_k(
    const float* __restrict__ QKVI, const float* __restrict__ Ef,
    const int* __restrict__ rowstart, const int* __restrict__ csr,
    const int* __restrict__ tgt, float* __restrict__ agg)
{
  __shared__ int   s_eid[MAXDEG];
  __shared__ int   s_tgt[MAXDEG];
  __shared__ float s_sc[HEADS][MAXDEGP];   // scores, then weights in-place
  __shared__ unsigned char s_alive[MAXDEG];
  __shared__ float s_self[8];
  __shared__ float s_wself[8];

  const float scl = 0.17677669529663687f;
  int i = blockIdx.x;
  int base = rowstart[i];
  int deg = rowstart[i + 1] - base;
  if (deg > MAXDEG) deg = MAXDEG;
  int tid = threadIdx.x;
  int w = tid >> 6, l = tid & 63;
  int h = tid >> 5, d = tid & 31;

  for (int t = tid; t < deg; t += 256) {
    int e = csr[base + t];
    s_eid[t] = e;
    s_tgt[t] = tgt[e];
  }
  __syncthreads();

  // Q_i: lane l holds dims 4l..4l+3 (head = l>>3)
  float4 q4 = *(const float4*)&QKVI[(size_t)i * 1024 + 4 * l];

  // self score (wave 0): Q_i . K_i per head
  if (w == 0) {
    float4 k4 = *(const float4*)&QKVI[(size_t)i * 1024 + 256 + 4 * l];
    float c = dot4(q4, k4);
#pragma unroll
    for (int off = 1; off <= 4; off <<= 1) c += __shfl_xor(c, off);
    if ((l & 7) == 0) s_self[l >> 3] = c * scl;
  }

  // edge logits: waves split edges; logit = ef.(q+k) + q.k per head
  for (int t = w; t < deg; t += 4) {
    int e = s_eid[t], tt = s_tgt[t];
    float4 ef = *(const float4*)&Ef[(size_t)e * 256 + 4 * l];
    float4 k4 = *(const float4*)&QKVI[(size_t)tt * 1024 + 256 + 4 * l];
    float c = dot4(q4, ef) + dot4(ef, k4) + dot4(q4, k4);
#pragma unroll
    for (int off = 1; off <= 4; off <<= 1) c += __shfl_xor(c, off);
    if ((l & 7) == 0) s_sc[l >> 3][t] = c * scl;
  }

  // dedup (keep max eid per tgt), drop self-target
  for (int t = tid; t < deg; t += 256) {
    int tt = s_tgt[t], ee = s_eid[t];
    bool alive = (tt != i);
    if (alive)
      for (int u = 0; u < deg; ++u)
        if (s_tgt[u] == tt && s_eid[u] > ee) { alive = false; break; }
    s_alive[t] = alive ? 1 : 0;
  }
  __syncthreads();

  // softmax: 32 lanes per head, in-place weights
  {
    float m = s_self[h];
    for (int t = d; t < deg; t += 32)
      if (s_alive[t]) m = fmaxf(m, s_sc[h][t]);
#pragma unroll
    for (int off = 16; off > 0; off >>= 1) m = fmaxf(m, __shfl_xor(m, off, 32));
    float lsum = 0.f;
    for (int t = d; t < deg; t += 32) {
      float wv = s_alive[t] ? expf(s_sc[h][t] - m) : 0.f;
      s_sc[h][t] = wv;
      lsum += wv;
    }
#pragma unroll
    for (int off = 16; off > 0; off >>= 1) lsum += __shfl_xor(lsum, off, 32);
    float wself = expf(s_self[h] - m);
    float inv = 1.f / (lsum + wself);
    if (d == 0) s_wself[h] = wself * inv;
    for (int t = d; t < deg; t += 32) s_sc[h][t] *= inv;
  }
  __syncthreads();

  // aggregate V (cols 512..767 of QKVI); col = tid -> coalesced
  int col = tid;
  float accv = s_wself[h] * QKVI[(size_t)i * 1024 + 512 + col];
  for (int t = 0; t < deg; ++t)
    if (s_alive[t])
      accv += s_sc[h][t] * QKVI[(size_t)s_tgt[t] * 1024 + 512 + col];
  agg[(size_t)i * 256 + col] = accv;
}

// ---------------------------------------------------------------------------
// LayerNorm(x_proj + preo)
// ---------------------------------------------------------------------------
__global__ __launch_bounds__(256) void ln_k(
    const float* __restrict__ QKVI, const float* __restrict__ preo,
    const float* __restrict__ g, const float* __restrict__ b,
    float* __restrict__ out)
{
  int i = blockIdx.x, c = threadIdx.x;
  float v = QKVI[(size_t)i * 1024 + 768 + c] + preo[(size_t)i * 256 + c];
  float s1 = v, s2 = v * v;
#pragma unroll
  for (int off = 32; off > 0; off >>= 1) {
    s1 += __shfl_xor(s1, off, 64);
    s2 += __shfl_xor(s2, off, 64);
  }
  __shared__ float r1[4], r2[4];
  int w = c >> 6;
  if ((c & 63) == 0) { r1[w] = s1; r2[w] = s2; }
  __syncthreads();
  s1 = r1[0] + r1[1] + r1[2] + r1[3];
  s2 = r2[0] + r2[1] + r2[2] + r2[3];
  float mu  = s1 * (1.0f / 256.0f);
  float var = s2 * (1.0f / 256.0f) - mu * mu;
  out[(size_t)i * 256 + c] = (v - mu) * rsqrtf(var + 1e-5f) * g[c] + b[c];
}

// ---------------------------------------------------------------------------
extern "C" void kernel_launch(void* const* d_in, const int* in_sizes, int n_in,
                              void* d_out, int out_size, void* d_ws, size_t ws_size,
                              hipStream_t stream) {
  (void)in_sizes; (void)n_in; (void)out_size; (void)ws_size;
  const float* x  = (const float*)d_in[0];
  const int*   ei = (const int*)d_in[1];
  const float* ea = (const float*)d_in[2];
  const float* Wq = (const float*)d_in[3];  const float* bq = (const float*)d_in[4];
  const float* Wk = (const float*)d_in[5];  const float* bk = (const float*)d_in[6];
  const float* Wv = (const float*)d_in[7];  const float* bv = (const float*)d_in[8];
  const float* We = (const float*)d_in[9];  const float* be = (const float*)d_in[10];
  const float* Wo = (const float*)d_in[11]; const float* bo = (const float*)d_in[12];
  const float* Wi = (const float*)d_in[13]; const float* bi = (const float*)d_in[14];
  const float* lng = (const float*)d_in[15]; const float* lnb = (const float*)d_in[16];

  const int* src = ei;
  const int* tgt = ei + N_EDGES;

  char* ws = (char*)d_ws;
  u16*   WcatT   = (u16*)(ws + 0);              //  512 KB
  u16*   WeT     = (u16*)(ws + 524288);         //  128 KB
  u16*   WoT     = (u16*)(ws + 655360);         //  128 KB
  float* bcat    = (float*)(ws + 786432);       //    4 KB
  float* QKVI    = (float*)(ws + 790528);       //   16 MB
  int*   deg     = (int*)(ws + 17567744);       //   16 KB
  int*   rowstart= (int*)(ws + 17584128);       //   16.25 KB
  int*   cursor  = (int*)(ws + 17600768);       //   16 KB
  int*   csr     = (int*)(ws + 17617152);       //  512 KB
  float* agg     = (float*)(ws + 18141440);     //    4 MB
  float* preo    = (float*)(ws + 22335744);     //    4 MB

  float* outN = (float*)d_out;
  float* outE = (float*)d_out + (size_t)N_NODES * DIM;

  hipMemsetAsync(deg, 0, N_NODES * sizeof(int), stream);

  prep_w_k<<<1536, 256, 0, stream>>>(Wq, Wk, Wv, Wi, We, Wo, bq, bk, bv, bi,
                                     WcatT, WeT, WoT, bcat);

  hist_k<<<N_EDGES / 256, 256, 0, stream>>>(src, deg);
  scan_k<<<1, 1024, 0, stream>>>(deg, rowstart, cursor);
  scatter_k<<<N_EDGES / 256, 256, 0, stream>>>(src, cursor, csr);

  // merged: edge_out = ea @ We + be  AND  QKVI = x @ [Wq|Wk|Wv|Wi] + bcat
  gemm_all_k<<<2304, 256, 0, stream>>>(ea, WeT, be, outE, x, WcatT, bcat, QKVI);

  // fused logits + softmax + V aggregation
  node_attn_k<<<N_NODES, 256, 0, stream>>>(QKVI, outE, rowstart, csr, tgt, agg);

  // preo = agg @ Wo + bo
  gemm64_k<<<N_NODES / 64, 256, 0, stream>>>(agg, WoT, bo, preo);

  ln_k<<<N_NODES, 256, 0, stream>>>(QKVI, preo, lng, lnb, outN);
}